// Round 1
// baseline (477.157 us; speedup 1.0000x reference)
//
#include <hip/hip_runtime.h>

// Problem constants
static constexpr int CB = 4;     // batch
static constexpr int CC = 320;   // input channels
static constexpr int CT = 9;     // frames
static constexpr int HW = 1024;  // 32*32
static constexpr int C2 = 160;   // conv output channels
static constexpr int NP = 32;    // b * (T-1) pair count
static constexpr size_t F_SZ = (size_t)NP * HW * C2;  // floats per f-tensor (5,242,880)
static constexpr int ROWF = 172; // padded LDS row stride (floats); 172*4B = 688B, 16B-aligned,
                                 // 43 float4/row -> bank-quad = 3*row mod 8 spreads all 8 quads

// ---------------------------------------------------------------------------
// Kernel 1: 1x1 convs.  For (bb, tt, o): f0 = W0 . x[bb,:,tt,:],  f1 = W1 . x[bb,:,tt+1,:]
// Stored scrambled per the reference's (b,o,t,hw)->(b*t,160,hw) reshape:
//   n = bb*8 + o/20 ; o' = 8*(o%20) + tt ;  fT[n][pixel][o']
// ---------------------------------------------------------------------------
__global__ __launch_bounds__(256)
void conv_kernel(const float* __restrict__ x, const float* __restrict__ w0,
                 const float* __restrict__ w1,
                 float* __restrict__ f0T, float* __restrict__ f1T) {
  __shared__ float xL[32 * 324];  // [px][c], pad 320->324
  const int pt = blockIdx.x;      // pixel tile (image row), 0..31
  const int tt = blockIdx.y;      // pair index 0..7
  const int bb = blockIdx.z;      // batch 0..3
  const int tid = threadIdx.x;
  const int og = tid & 31;        // o-group: 5 outputs each
  const int pg = tid >> 5;        // px-group: 4 pixels each
  const int o0 = og * 5, px0 = pg * 4;
  const int q = og >> 2;          // = o/20
  const int r5 = (og & 3) * 5;    // = o0 % 20
  const float4* xL4 = reinterpret_cast<const float4*>(xL);

  for (int half = 0; half < 2; ++half) {
    const int f = tt + half;  // frame index
    const float4* w4 = reinterpret_cast<const float4*>(half ? w1 : w0);
    float* fT = half ? f1T : f0T;
    __syncthreads();  // protect xL reuse between halves
    for (int idx = tid; idx < CC * 32; idx += 256) {
      int c = idx >> 5, px = idx & 31;
      xL[px * 324 + c] =
          x[((size_t)(bb * CC + c) * CT + f) * HW + pt * 32 + px];
    }
    __syncthreads();

    float acc[4][5];
#pragma unroll
    for (int p = 0; p < 4; ++p)
#pragma unroll
      for (int j = 0; j < 5; ++j) acc[p][j] = 0.f;

#pragma unroll 2
    for (int c4 = 0; c4 < 80; ++c4) {
      float4 xv[4], wv[5];
#pragma unroll
      for (int p = 0; p < 4; ++p) xv[p] = xL4[(px0 + p) * 81 + c4];
#pragma unroll
      for (int j = 0; j < 5; ++j) wv[j] = w4[(o0 + j) * 80 + c4];
#pragma unroll
      for (int p = 0; p < 4; ++p)
#pragma unroll
        for (int j = 0; j < 5; ++j) {
          acc[p][j] += xv[p].x * wv[j].x + xv[p].y * wv[j].y +
                       xv[p].z * wv[j].z + xv[p].w * wv[j].w;
        }
    }

    const size_t nb = (size_t)(bb * 8 + q) * ((size_t)HW * C2);
#pragma unroll
    for (int p = 0; p < 4; ++p) {
      const size_t rowb = nb + (size_t)(pt * 32 + px0 + p) * C2 + tt;
#pragma unroll
      for (int j = 0; j < 5; ++j) {
        fT[rowb + 8 * (r5 + j)] = acc[p][j];
      }
    }
  }
}

// ---------------------------------------------------------------------------
// Kernel 2: 2x2 avg-pool of f1 over the j pixel grid: f1p[n][Y*16+X][c]
// ---------------------------------------------------------------------------
__global__ __launch_bounds__(256)
void pool_kernel(const float* __restrict__ f1T, float* __restrict__ f1p) {
  const int id = blockIdx.x * 256 + threadIdx.x;  // over 32*256*40 float4 outs
  if (id >= NP * 256 * 40) return;
  const int c4 = id % 40;
  const int j = (id / 40) & 255;
  const int n = id / (40 * 256);
  const int X = j & 15, Y = j >> 4;
  const float4* src =
      reinterpret_cast<const float4*>(f1T + (size_t)n * HW * C2);
  const int r00 = ((2 * Y) * 32 + 2 * X) * 40 + c4;
  float4 a = src[r00], b = src[r00 + 40], c = src[r00 + 32 * 40],
         d = src[r00 + 32 * 40 + 40];
  float4 r;
  r.x = 0.25f * (a.x + b.x + c.x + d.x);
  r.y = 0.25f * (a.y + b.y + c.y + d.y);
  r.z = 0.25f * (a.z + b.z + c.z + d.z);
  r.w = 0.25f * (a.w + b.w + c.w + d.w);
  reinterpret_cast<float4*>(f1p)[((size_t)n * 256 + j) * 40 + c4] = r;
}

// ---------------------------------------------------------------------------
// Kernel 3: fused correlation + pyramid sampling.  Block = (n, y-row).
// Level 0: integer offsets -> direct dots. Level 1: 8x8 corner dots + bilinear
// combine with weights in {0, 0.5}.
// ---------------------------------------------------------------------------
__global__ __launch_bounds__(256)
void corr_kernel(const float* __restrict__ f0T, const float* __restrict__ f1T,
                 const float* __restrict__ f1p, float* __restrict__ out) {
  __shared__ float f0L[32 * ROWF];
  __shared__ float f1L[32 * ROWF];
  __shared__ float cornerL[8 * 32 * 9];  // [v][xx][u], stride 9 -> conflict-free
  const int y = blockIdx.x;   // 0..31
  const int n = blockIdx.y;   // 0..31
  const int bb = n >> 3, q = n & 7;
  const int tid = threadIdx.x;
  const int xx = tid & 31;
  const int hi = tid >> 5;    // 0..7: dxi for level 0 (<7), u for level 1
  const float inv = 1.f / 160.f;
  // out flat index = (bb*784 + q)*1024 + ch*8192 + y*32 + x
  const size_t obase = (size_t)(bb * 784 + q) * 1024 + (size_t)y * 32;

  // stage f0 row (i = y*32 + 0..31)
  {
    const float4* src = reinterpret_cast<const float4*>(
        f0T + (size_t)n * HW * C2 + (size_t)y * 32 * C2);
    for (int idx = tid; idx < 32 * 40; idx += 256) {
      int rr = idx / 40, c4 = idx % 40;
      *reinterpret_cast<float4*>(f0L + rr * ROWF + c4 * 4) = src[rr * 40 + c4];
    }
  }

  // ---- level 0 ----
  for (int dyi = 0; dyi < 7; ++dyi) {
    const int yy = y + dyi - 3;
    const bool inr = (unsigned)yy < 32u;
    __syncthreads();  // previous iter's readers done (also fences f0L stage)
    if (inr) {
      const float4* src = reinterpret_cast<const float4*>(
          f1T + (size_t)n * HW * C2 + (size_t)yy * 32 * C2);
      for (int idx = tid; idx < 32 * 40; idx += 256) {
        int rr = idx / 40, c4 = idx % 40;
        *reinterpret_cast<float4*>(f1L + rr * ROWF + c4 * 4) =
            src[rr * 40 + c4];
      }
    }
    __syncthreads();
    if (hi < 7) {
      const int x2 = xx + hi - 3;
      float val = 0.f;
      if (inr && (unsigned)x2 < 32u) {
        const float4* a = reinterpret_cast<const float4*>(f0L + xx * ROWF);
        const float4* b = reinterpret_cast<const float4*>(f1L + x2 * ROWF);
        float4 s = {0.f, 0.f, 0.f, 0.f};
#pragma unroll 8
        for (int c4 = 0; c4 < 40; ++c4) {
          float4 av = a[c4], bv = b[c4];
          s.x += av.x * bv.x;
          s.y += av.y * bv.y;
          s.z += av.z * bv.z;
          s.w += av.w * bv.w;
        }
        val = (s.x + s.y + s.z + s.w) * inv;
      }
      out[obase + (size_t)(hi * 7 + dyi) * 8192 + xx] = val;
    }
  }

  // ---- level 1: corner dots ----
  const int Y0 = (y >> 1) - 3;
  for (int v = 0; v < 8; ++v) {
    const int Y = Y0 + v;
    const bool inr = (unsigned)Y < 16u;
    __syncthreads();
    if (inr) {
      const float4* src = reinterpret_cast<const float4*>(
          f1p + ((size_t)n * 256 + (size_t)Y * 16) * C2);
      for (int idx = tid; idx < 16 * 40; idx += 256) {
        int rr = idx / 40, c4 = idx % 40;
        *reinterpret_cast<float4*>(f1L + rr * ROWF + c4 * 4) =
            src[rr * 40 + c4];
      }
    }
    __syncthreads();
    const int X = (xx >> 1) - 3 + hi;
    float val = 0.f;
    if (inr && (unsigned)X < 16u) {
      const float4* a = reinterpret_cast<const float4*>(f0L + xx * ROWF);
      const float4* b = reinterpret_cast<const float4*>(f1L + X * ROWF);
      float4 s = {0.f, 0.f, 0.f, 0.f};
#pragma unroll 8
      for (int c4 = 0; c4 < 40; ++c4) {
        float4 av = a[c4], bv = b[c4];
        s.x += av.x * bv.x;
        s.y += av.y * bv.y;
        s.z += av.z * bv.z;
        s.w += av.w * bv.w;
      }
      val = (s.x + s.y + s.z + s.w) * inv;
    }
    cornerL[(v * 32 + xx) * 9 + hi] = val;
  }
  __syncthreads();

  // ---- level 1: bilinear combine (weights 0 or 0.5) ----
  const float wy = (y & 1) ? 0.5f : 0.f;
  for (int idx = tid; idx < 32 * 49; idx += 256) {
    const int x2 = idx & 31;
    const int k = idx >> 5;  // 0..48
    const int dxi = k / 7, dyi = k % 7;
    const float wx = (x2 & 1) ? 0.5f : 0.f;
    const float* c0 = cornerL + (dyi * 32 + x2) * 9 + dxi;
    const float* c1 = c0 + 32 * 9;
    const float val = (1.f - wx) * ((1.f - wy) * c0[0] + wy * c1[0]) +
                      wx * ((1.f - wy) * c0[1] + wy * c1[1]);
    out[obase + (size_t)(49 + k) * 8192 + x2] = val;
  }
}

// ---------------------------------------------------------------------------
extern "C" void kernel_launch(void* const* d_in, const int* in_sizes, int n_in,
                              void* d_out, int out_size, void* d_ws,
                              size_t ws_size, hipStream_t stream) {
  const float* x = (const float*)d_in[0];
  const float* w0 = (const float*)d_in[1];
  const float* w1 = (const float*)d_in[2];
  float* f0T = (float*)d_ws;           // [32][1024][160]
  float* f1T = f0T + F_SZ;             // [32][1024][160]
  float* f1p = f1T + F_SZ;             // [32][256][160]
  float* out = (float*)d_out;

  conv_kernel<<<dim3(32, 8, 4), 256, 0, stream>>>(x, w0, w1, f0T, f1T);
  pool_kernel<<<dim3(1280), 256, 0, stream>>>(f1T, f1p);
  corr_kernel<<<dim3(32, 32), 256, 0, stream>>>(f0T, f1T, f1p, out);
}

// Round 2
// 341.479 us; speedup vs baseline: 1.3973x; 1.3973x over previous
//
#include <hip/hip_runtime.h>

// Problem constants
static constexpr int CB = 4;     // batch
static constexpr int CC = 320;   // input channels
static constexpr int CT = 9;     // frames
static constexpr int HW = 1024;  // 32*32
static constexpr int C2 = 160;   // conv output channels
static constexpr int NP = 32;    // b * (T-1) pair count
static constexpr size_t F_SZ = (size_t)NP * HW * C2;  // floats per f-tensor
static constexpr int ROWF = 172; // padded LDS row stride (floats) for corr

// ---------------------------------------------------------------------------
// Kernel 1: 1x1 convs as a register-blocked GEMM with wave-uniform (scalar)
// weight loads. Block = (px-tile of 128, frame f, batch bb), 512 threads.
// Wave w (0..7): mat = w>>2 (0 -> W0 as f0 of pair tt=f; 1 -> W1 as f1 of
// pair tt=f-1); owns o-rows [(w&3)*40, +40). Lane owns 2 consecutive pixels.
// Inner loop over c: x via one coalesced dwordx2, w via scalar loads (uniform
// address), 80 v_fmac_f32. No LDS, no barriers.
// Output scrambled per the reference reshape (verified in round 1):
//   n = bb*8 + o/20 ; o' = 8*(o%20) + tt ; fT[n][px][o']
// ---------------------------------------------------------------------------
__global__ __launch_bounds__(512)
void conv_kernel(const float* __restrict__ x, const float* __restrict__ w0,
                 const float* __restrict__ w1,
                 float* __restrict__ f0T, float* __restrict__ f1T) {
  const int tile = blockIdx.x;  // 0..7
  const int f = blockIdx.y;     // 0..8
  const int bb = blockIdx.z;    // 0..3
  const int wave = __builtin_amdgcn_readfirstlane(threadIdx.x >> 6);
  const int lane = threadIdx.x & 63;
  const int mat = wave >> 2;    // 0 = W0, 1 = W1
  if (mat == 0 && f == 8) return;  // frame 8 is never an f0
  if (mat == 1 && f == 0) return;  // frame 0 is never an f1
  const int o0w = (wave & 3) * 40;
  const int tt = mat ? (f - 1) : f;
  const int px = tile * 128 + lane * 2;

  const float* __restrict__ wbase = (mat ? w1 : w0) + (size_t)o0w * 320;
  const float* __restrict__ xp =
      x + ((size_t)(bb * CC) * CT + f) * HW + px;  // + c*9216 walks channels

  float2 acc[40];
#pragma unroll
  for (int j = 0; j < 40; ++j) acc[j] = make_float2(0.f, 0.f);

  float2 xv = *reinterpret_cast<const float2*>(xp);
  for (int c = 0; c < 319; ++c) {
    float2 xn =
        *reinterpret_cast<const float2*>(xp + (size_t)(c + 1) * (CT * HW));
#pragma unroll
    for (int j = 0; j < 40; ++j) {
      const float wv = wbase[j * 320 + c];  // wave-uniform -> s_load
      acc[j].x = fmaf(wv, xv.x, acc[j].x);
      acc[j].y = fmaf(wv, xv.y, acc[j].y);
    }
    xv = xn;
  }
#pragma unroll
  for (int j = 0; j < 40; ++j) {
    const float wv = wbase[j * 320 + 319];
    acc[j].x = fmaf(wv, xv.x, acc[j].x);
    acc[j].y = fmaf(wv, xv.y, acc[j].y);
  }

  // scatter-store into the scrambled f layout
  float* __restrict__ fT = mat ? f1T : f0T;
#pragma unroll
  for (int j = 0; j < 40; ++j) {
    const int o = o0w + j;
    const int n = bb * 8 + o / 20;
    const int op = 8 * (o % 20) + tt;
    const size_t addr = ((size_t)n * HW + px) * C2 + op;
    fT[addr] = acc[j].x;
    fT[addr + C2] = acc[j].y;
  }
}

// ---------------------------------------------------------------------------
// Kernel 2: 2x2 avg-pool of f1 over the j pixel grid: f1p[n][Y*16+X][c]
// ---------------------------------------------------------------------------
__global__ __launch_bounds__(256)
void pool_kernel(const float* __restrict__ f1T, float* __restrict__ f1p) {
  const int id = blockIdx.x * 256 + threadIdx.x;  // over 32*256*40 float4 outs
  if (id >= NP * 256 * 40) return;
  const int c4 = id % 40;
  const int j = (id / 40) & 255;
  const int n = id / (40 * 256);
  const int X = j & 15, Y = j >> 4;
  const float4* src =
      reinterpret_cast<const float4*>(f1T + (size_t)n * HW * C2);
  const int r00 = ((2 * Y) * 32 + 2 * X) * 40 + c4;
  float4 a = src[r00], b = src[r00 + 40], c = src[r00 + 32 * 40],
         d = src[r00 + 32 * 40 + 40];
  float4 r;
  r.x = 0.25f * (a.x + b.x + c.x + d.x);
  r.y = 0.25f * (a.y + b.y + c.y + d.y);
  r.z = 0.25f * (a.z + b.z + c.z + d.z);
  r.w = 0.25f * (a.w + b.w + c.w + d.w);
  reinterpret_cast<float4*>(f1p)[((size_t)n * 256 + j) * 40 + c4] = r;
}

// ---------------------------------------------------------------------------
// Kernel 3: fused correlation + pyramid sampling.  Block = (n, y-row).
// Level 0: integer offsets -> direct dots. Level 1: 8x8 corner dots + bilinear
// combine with weights in {0, 0.5}.
// ---------------------------------------------------------------------------
__global__ __launch_bounds__(256)
void corr_kernel(const float* __restrict__ f0T, const float* __restrict__ f1T,
                 const float* __restrict__ f1p, float* __restrict__ out) {
  __shared__ float f0L[32 * ROWF];
  __shared__ float f1L[32 * ROWF];
  __shared__ float cornerL[8 * 32 * 9];  // [v][xx][u], stride 9 -> conflict-free
  const int y = blockIdx.x;   // 0..31
  const int n = blockIdx.y;   // 0..31
  const int bb = n >> 3, q = n & 7;
  const int tid = threadIdx.x;
  const int xx = tid & 31;
  const int hi = tid >> 5;    // 0..7: dxi for level 0 (<7), u for level 1
  const float inv = 1.f / 160.f;
  const size_t obase = (size_t)(bb * 784 + q) * 1024 + (size_t)y * 32;

  // stage f0 row (i = y*32 + 0..31)
  {
    const float4* src = reinterpret_cast<const float4*>(
        f0T + (size_t)n * HW * C2 + (size_t)y * 32 * C2);
    for (int idx = tid; idx < 32 * 40; idx += 256) {
      int rr = idx / 40, c4 = idx % 40;
      *reinterpret_cast<float4*>(f0L + rr * ROWF + c4 * 4) = src[rr * 40 + c4];
    }
  }

  // ---- level 0 ----
  for (int dyi = 0; dyi < 7; ++dyi) {
    const int yy = y + dyi - 3;
    const bool inr = (unsigned)yy < 32u;
    __syncthreads();  // previous iter's readers done (also fences f0L stage)
    if (inr) {
      const float4* src = reinterpret_cast<const float4*>(
          f1T + (size_t)n * HW * C2 + (size_t)yy * 32 * C2);
      for (int idx = tid; idx < 32 * 40; idx += 256) {
        int rr = idx / 40, c4 = idx % 40;
        *reinterpret_cast<float4*>(f1L + rr * ROWF + c4 * 4) =
            src[rr * 40 + c4];
      }
    }
    __syncthreads();
    if (hi < 7) {
      const int x2 = xx + hi - 3;
      float val = 0.f;
      if (inr && (unsigned)x2 < 32u) {
        const float4* a = reinterpret_cast<const float4*>(f0L + xx * ROWF);
        const float4* b = reinterpret_cast<const float4*>(f1L + x2 * ROWF);
        float4 s = {0.f, 0.f, 0.f, 0.f};
#pragma unroll 8
        for (int c4 = 0; c4 < 40; ++c4) {
          float4 av = a[c4], bv = b[c4];
          s.x += av.x * bv.x;
          s.y += av.y * bv.y;
          s.z += av.z * bv.z;
          s.w += av.w * bv.w;
        }
        val = (s.x + s.y + s.z + s.w) * inv;
      }
      out[obase + (size_t)(hi * 7 + dyi) * 8192 + xx] = val;
    }
  }

  // ---- level 1: corner dots ----
  const int Y0 = (y >> 1) - 3;
  for (int v = 0; v < 8; ++v) {
    const int Y = Y0 + v;
    const bool inr = (unsigned)Y < 16u;
    __syncthreads();
    if (inr) {
      const float4* src = reinterpret_cast<const float4*>(
          f1p + ((size_t)n * 256 + (size_t)Y * 16) * C2);
      for (int idx = tid; idx < 16 * 40; idx += 256) {
        int rr = idx / 40, c4 = idx % 40;
        *reinterpret_cast<float4*>(f1L + rr * ROWF + c4 * 4) =
            src[rr * 40 + c4];
      }
    }
    __syncthreads();
    const int X = (xx >> 1) - 3 + hi;
    float val = 0.f;
    if (inr && (unsigned)X < 16u) {
      const float4* a = reinterpret_cast<const float4*>(f0L + xx * ROWF);
      const float4* b = reinterpret_cast<const float4*>(f1L + X * ROWF);
      float4 s = {0.f, 0.f, 0.f, 0.f};
#pragma unroll 8
      for (int c4 = 0; c4 < 40; ++c4) {
        float4 av = a[c4], bv = b[c4];
        s.x += av.x * bv.x;
        s.y += av.y * bv.y;
        s.z += av.z * bv.z;
        s.w += av.w * bv.w;
      }
      val = (s.x + s.y + s.z + s.w) * inv;
    }
    cornerL[(v * 32 + xx) * 9 + hi] = val;
  }
  __syncthreads();

  // ---- level 1: bilinear combine (weights 0 or 0.5) ----
  const float wy = (y & 1) ? 0.5f : 0.f;
  for (int idx = tid; idx < 32 * 49; idx += 256) {
    const int x2 = idx & 31;
    const int k = idx >> 5;  // 0..48
    const int dxi = k / 7, dyi = k % 7;
    const float wx = (x2 & 1) ? 0.5f : 0.f;
    const float* c0 = cornerL + (dyi * 32 + x2) * 9 + dxi;
    const float* c1 = c0 + 32 * 9;
    const float val = (1.f - wx) * ((1.f - wy) * c0[0] + wy * c1[0]) +
                      wx * ((1.f - wy) * c0[1] + wy * c1[1]);
    out[obase + (size_t)(49 + k) * 8192 + x2] = val;
  }
}

// ---------------------------------------------------------------------------
extern "C" void kernel_launch(void* const* d_in, const int* in_sizes, int n_in,
                              void* d_out, int out_size, void* d_ws,
                              size_t ws_size, hipStream_t stream) {
  const float* x = (const float*)d_in[0];
  const float* w0 = (const float*)d_in[1];
  const float* w1 = (const float*)d_in[2];
  float* f0T = (float*)d_ws;           // [32][1024][160]
  float* f1T = f0T + F_SZ;             // [32][1024][160]
  float* f1p = f1T + F_SZ;             // [32][256][160]
  float* out = (float*)d_out;

  conv_kernel<<<dim3(8, 9, 4), 512, 0, stream>>>(x, w0, w1, f0T, f1T);
  pool_kernel<<<dim3(1280), 256, 0, stream>>>(f1T, f1p);
  corr_kernel<<<dim3(32, 32), 256, 0, stream>>>(f0T, f1T, f1p, out);
}

// Round 3
// 163.221 us; speedup vs baseline: 2.9234x; 2.0921x over previous
//
#include <hip/hip_runtime.h>
#include <hip/hip_bf16.h>

typedef __attribute__((ext_vector_type(8))) short short8;   // 8 bf16 (4 VGPRs)
typedef __attribute__((ext_vector_type(4))) short short4v;  // 4 bf16 (8 B)
typedef __attribute__((ext_vector_type(4))) float f32x4;    // MFMA acc

// Problem constants
static constexpr int CC = 320;   // input channels
static constexpr int HW = 1024;  // 32*32
static constexpr int C2 = 160;   // conv output channels
static constexpr size_t F_SZ = 32ull * HW * C2;  // floats per g tensor (5,242,880)
static constexpr int ROWF = 172;  // padded LDS row stride (floats), 16B-aligned rows
static constexpr int KSTEPS = 10; // K=320 in steps of 32
static constexpr int WPLANE = 160 * 40;  // shorts per (mat,hl) w-plane (padded 32->40)
static constexpr int WKS = 4 * WPLANE;   // shorts per k-step image (25600)

__device__ inline short bfh(float v) {
  __hip_bfloat16 h = __float2bfloat16(v);
  return *reinterpret_cast<short*>(&h);
}
__device__ inline float bff(short s) {
  union { unsigned u; float f; } c;
  c.u = ((unsigned)(unsigned short)s) << 16;
  return c.f;
}

// ---------------------------------------------------------------------------
// Kernel 0: pre-split w into bf16 (hi, lo) planes tiled exactly as the conv's
// LDS image: wp[ks][mat][hl][o 160][kk 40] (kk 32..39 = zero pad).
// ---------------------------------------------------------------------------
__global__ __launch_bounds__(256)
void wprep_kernel(const float* __restrict__ w0, const float* __restrict__ w1,
                  short* __restrict__ wp) {
  const int id = blockIdx.x * 256 + threadIdx.x;
  if (id >= KSTEPS * WKS) return;
  const int kk = id % 40;
  const int o = (id / 40) % 160;
  const int hl = (id / 6400) % 2;
  const int mat = (id / 12800) % 2;
  const int ks = id / 25600;
  short outv = 0;
  if (kk < 32) {
    const float v = (mat ? w1 : w0)[o * 320 + ks * 32 + kk];
    const short hb = bfh(v);
    outv = hl ? bfh(v - bff(hb)) : hb;
  }
  wp[id] = outv;
}

// ---------------------------------------------------------------------------
// Kernel 1: 1x1 convs via split-bf16 MFMA (wh*xh + wh*xl + wl*xh).
// Block = (px-tile 64, frame f, batch bb), 256 thr (4 waves).
// Wave: mat = w>>1 (0->W0/f0, 1->W1/f1), n-frags (w&1)*2..+1; per wave
// 10 m-frags x 2 n-frags of 16x16, acc 80 VGPRs.
// Output: NATURAL layout g[bb][tt][o][px] -> fully coalesced 64B stores.
// A/B frag k-map: k = (lane>>4)*8 + j for BOTH operands (consistency is all
// that matters; C/D layout col=lane&15,row=(lane>>4)*4+reg is HW-verified).
// ---------------------------------------------------------------------------
__global__ __launch_bounds__(256)
void conv_mfma(const float* __restrict__ x, const short* __restrict__ wprep,
               float* __restrict__ g0, float* __restrict__ g1) {
  __shared__ __align__(16) short wL[4 * WPLANE];  // [mat*2+hl][160][40]
  __shared__ __align__(16) short xL[2][2560];     // [hl][px 64][kk 40]
  const int pxt = blockIdx.x;  // 0..15
  const int f = blockIdx.y;    // 0..8
  const int bb = blockIdx.z;   // 0..3
  const int tid = threadIdx.x;
  const int lane = tid & 63;
  const int wave = __builtin_amdgcn_readfirstlane(tid >> 6);
  const int lr = lane & 15, kg = lane >> 4;
  const int mat = wave >> 1;
  const int nf0 = (wave & 1) * 2;
  const bool active = mat ? (f >= 1) : (f < 8);
  const int tt = mat ? (f - 1) : f;
  const int p0 = pxt * 64;

  f32x4 acc[10][2];
#pragma unroll
  for (int m = 0; m < 10; ++m)
#pragma unroll
    for (int nfi = 0; nfi < 2; ++nfi)
#pragma unroll
      for (int r = 0; r < 4; ++r) acc[m][nfi][r] = 0.f;

  const size_t xbase = (size_t)bb * CC * 9216 + (size_t)f * 1024 + p0;
  float xr[2][4];
  // preload x slice ks=0 into regs
#pragma unroll
  for (int it = 0; it < 2; ++it) {
    const int item = tid + it * 256, px = item & 63, cg = item >> 6;
    const float* xp = x + xbase + (size_t)(cg * 4) * 9216 + px;
#pragma unroll
    for (int j = 0; j < 4; ++j) xr[it][j] = xp[(size_t)j * 9216];
  }

  for (int ks = 0; ks < KSTEPS; ++ks) {
    __syncthreads();  // LDS free (previous compute done)
    // stage w planes (plain uint4 copy of the pre-tiled image)
    {
      const uint4* src = reinterpret_cast<const uint4*>(wprep + (size_t)ks * WKS);
      uint4* dst = reinterpret_cast<uint4*>(wL);
#pragma unroll
      for (int i = 0; i < 13; ++i) {
        const int idx = tid + i * 256;
        if (idx < 3200) dst[idx] = src[idx];
      }
    }
    // stage x from regs: convert to (h,l) bf16, transposed to [px][kk]
#pragma unroll
    for (int it = 0; it < 2; ++it) {
      const int item = tid + it * 256, px = item & 63, cg = item >> 6;
      short4v hv, lv;
#pragma unroll
      for (int j = 0; j < 4; ++j) {
        const float v = xr[it][j];
        const short hb = bfh(v);
        hv[j] = hb;
        lv[j] = bfh(v - bff(hb));
      }
      *reinterpret_cast<short4v*>(&xL[0][px * 40 + cg * 4]) = hv;
      *reinterpret_cast<short4v*>(&xL[1][px * 40 + cg * 4]) = lv;
    }
    __syncthreads();
    // prefetch next x slice (overlaps with MFMA below)
    if (ks + 1 < KSTEPS) {
#pragma unroll
      for (int it = 0; it < 2; ++it) {
        const int item = tid + it * 256, px = item & 63, cg = item >> 6;
        const float* xp =
            x + xbase + (size_t)((ks + 1) * 32 + cg * 4) * 9216 + px;
#pragma unroll
        for (int j = 0; j < 4; ++j) xr[it][j] = xp[(size_t)j * 9216];
      }
    }
    if (active) {
      short8 bx[2][2];
#pragma unroll
      for (int nfi = 0; nfi < 2; ++nfi)
#pragma unroll
        for (int hl = 0; hl < 2; ++hl)
          bx[nfi][hl] = *reinterpret_cast<const short8*>(
              &xL[hl][((nf0 + nfi) * 16 + lr) * 40 + kg * 8]);
      const short* wbm = wL + mat * 2 * WPLANE;
#pragma unroll
      for (int m = 0; m < 10; ++m) {
        const short8 ah = *reinterpret_cast<const short8*>(
            &wbm[(m * 16 + lr) * 40 + kg * 8]);
        const short8 al = *reinterpret_cast<const short8*>(
            &wbm[WPLANE + (m * 16 + lr) * 40 + kg * 8]);
#pragma unroll
        for (int nfi = 0; nfi < 2; ++nfi) {
          acc[m][nfi] = __builtin_amdgcn_mfma_f32_16x16x32_bf16(
              ah, bx[nfi][0], acc[m][nfi], 0, 0, 0);
          acc[m][nfi] = __builtin_amdgcn_mfma_f32_16x16x32_bf16(
              ah, bx[nfi][1], acc[m][nfi], 0, 0, 0);
          acc[m][nfi] = __builtin_amdgcn_mfma_f32_16x16x32_bf16(
              al, bx[nfi][0], acc[m][nfi], 0, 0, 0);
        }
      }
    }
  }
  if (active) {
    float* __restrict__ g = mat ? g1 : g0;
    const size_t gb = (size_t)(bb * 8 + tt) * C2 * HW;
#pragma unroll
    for (int m = 0; m < 10; ++m) {
      const int o_b = m * 16 + kg * 4;
#pragma unroll
      for (int nfi = 0; nfi < 2; ++nfi) {
        const int px = p0 + (nf0 + nfi) * 16 + lr;
#pragma unroll
        for (int r = 0; r < 4; ++r)
          g[gb + (size_t)(o_b + r) * HW + px] = acc[m][nfi][r];
      }
    }
  }
}

// ---------------------------------------------------------------------------
// Kernel 2: 2x2 avg-pool over the px grid, natural layout in and out:
// g1[row=nt*160+o][1024] -> g1p[row][256]
// ---------------------------------------------------------------------------
__global__ __launch_bounds__(256)
void pool_kernel(const float* __restrict__ g1, float* __restrict__ g1p) {
  const int id = blockIdx.x * 256 + threadIdx.x;
  if (id >= 32 * 160 * 16 * 8) return;
  const int X4 = id & 7, Y = (id >> 3) & 15;
  const int row = id >> 7;  // 0..5119
  const float4* G4 = reinterpret_cast<const float4*>(g1) + (size_t)row * 256;
  const float4 a = G4[Y * 16 + X4];      // row 2Y
  const float4 c = G4[Y * 16 + X4 + 8];  // row 2Y+1
  float2 r;
  r.x = 0.25f * (a.x + a.y + c.x + c.y);
  r.y = 0.25f * (a.z + a.w + c.z + c.w);
  reinterpret_cast<float2*>(g1p)[(size_t)row * 128 + Y * 8 + X4] = r;
}

// ---------------------------------------------------------------------------
// Kernel 3: fused correlation + pyramid sampling (compute phases unchanged
// from the passing round-2 kernel; staging now gathers from natural-layout
// g tensors, doing the (tt,r)->channel transpose on the fly).
// channel c (0..159): tt = c&7, r = c>>3, o = q*20 + r.
// ---------------------------------------------------------------------------
__global__ __launch_bounds__(256)
void corr_kernel(const float* __restrict__ g0, const float* __restrict__ g1,
                 const float* __restrict__ g1p, float* __restrict__ out) {
  __shared__ float f0L[32 * ROWF];
  __shared__ float f1L[32 * ROWF];
  __shared__ float cornerL[8 * 32 * 9];  // [v][xx][u], stride 9
  const int y = blockIdx.x;  // 0..31
  const int n = blockIdx.y;  // 0..31
  const int bb = n >> 3, q = n & 7;
  const int tid = threadIdx.x;
  const int xx = tid & 31;
  const int hi = tid >> 5;  // 0..7
  const float inv = 1.f / 160.f;
  const size_t obase = (size_t)(bb * 784 + q) * 1024 + (size_t)y * 32;
  const int chb = (bb * 8) * C2 + q * 20;  // + (c&7)*160 + (c>>3)

  // stage f0 row (transposed gather from g0)
  for (int idx = tid; idx < 5120; idx += 256) {
    const int c = idx >> 5, px = idx & 31;
    f0L[px * ROWF + c] =
        g0[(size_t)(chb + (c & 7) * C2 + (c >> 3)) * HW + y * 32 + px];
  }

  // ---- level 0 ----
  for (int dyi = 0; dyi < 7; ++dyi) {
    const int yy = y + dyi - 3;
    const bool inr = (unsigned)yy < 32u;
    __syncthreads();
    if (inr) {
      for (int idx = tid; idx < 5120; idx += 256) {
        const int c = idx >> 5, px = idx & 31;
        f1L[px * ROWF + c] =
            g1[(size_t)(chb + (c & 7) * C2 + (c >> 3)) * HW + yy * 32 + px];
      }
    }
    __syncthreads();
    if (hi < 7) {
      const int x2 = xx + hi - 3;
      float val = 0.f;
      if (inr && (unsigned)x2 < 32u) {
        const float4* a = reinterpret_cast<const float4*>(f0L + xx * ROWF);
        const float4* b = reinterpret_cast<const float4*>(f1L + x2 * ROWF);
        float4 s = {0.f, 0.f, 0.f, 0.f};
#pragma unroll 8
        for (int c4 = 0; c4 < 40; ++c4) {
          const float4 av = a[c4], bv = b[c4];
          s.x += av.x * bv.x;
          s.y += av.y * bv.y;
          s.z += av.z * bv.z;
          s.w += av.w * bv.w;
        }
        val = (s.x + s.y + s.z + s.w) * inv;
      }
      out[obase + (size_t)(hi * 7 + dyi) * 8192 + xx] = val;
    }
  }

  // ---- level 1: corner dots ----
  const int Y0 = (y >> 1) - 3;
  for (int v = 0; v < 8; ++v) {
    const int Y = Y0 + v;
    const bool inr = (unsigned)Y < 16u;
    __syncthreads();
    if (inr) {
      for (int idx = tid; idx < 2560; idx += 256) {
        const int c = idx >> 4, px = idx & 15;
        f1L[px * ROWF + c] =
            g1p[(size_t)(chb + (c & 7) * C2 + (c >> 3)) * 256 + Y * 16 + px];
      }
    }
    __syncthreads();
    const int X = (xx >> 1) - 3 + hi;
    float val = 0.f;
    if (inr && (unsigned)X < 16u) {
      const float4* a = reinterpret_cast<const float4*>(f0L + xx * ROWF);
      const float4* b = reinterpret_cast<const float4*>(f1L + X * ROWF);
      float4 s = {0.f, 0.f, 0.f, 0.f};
#pragma unroll 8
      for (int c4 = 0; c4 < 40; ++c4) {
        const float4 av = a[c4], bv = b[c4];
        s.x += av.x * bv.x;
        s.y += av.y * bv.y;
        s.z += av.z * bv.z;
        s.w += av.w * bv.w;
      }
      val = (s.x + s.y + s.z + s.w) * inv;
    }
    cornerL[(v * 32 + xx) * 9 + hi] = val;
  }
  __syncthreads();

  // ---- level 1: bilinear combine (weights 0 or 0.5) ----
  const float wy = (y & 1) ? 0.5f : 0.f;
  for (int idx = tid; idx < 32 * 49; idx += 256) {
    const int x2 = idx & 31;
    const int k = idx >> 5;  // 0..48
    const int dxi = k / 7, dyi = k % 7;
    const float wx = (x2 & 1) ? 0.5f : 0.f;
    const float* c0 = cornerL + (dyi * 32 + x2) * 9 + dxi;
    const float* c1 = c0 + 32 * 9;
    const float val = (1.f - wx) * ((1.f - wy) * c0[0] + wy * c1[0]) +
                      wx * ((1.f - wy) * c0[1] + wy * c1[1]);
    out[obase + (size_t)(49 + k) * 8192 + x2] = val;
  }
}

// ---------------------------------------------------------------------------
extern "C" void kernel_launch(void* const* d_in, const int* in_sizes, int n_in,
                              void* d_out, int out_size, void* d_ws,
                              size_t ws_size, hipStream_t stream) {
  const float* x = (const float*)d_in[0];
  const float* w0 = (const float*)d_in[1];
  const float* w1 = (const float*)d_in[2];
  float* g0 = (float*)d_ws;        // [4][8][160][1024]
  float* g1 = g0 + F_SZ;           // [4][8][160][1024]
  float* g1p = g1 + F_SZ;          // [4][8][160][256]
  short* wprep = (short*)(void*)g1p;  // overlapped: consumed before pool runs
  float* out = (float*)d_out;

  wprep_kernel<<<2000, 256, 0, stream>>>(w0, w1, wprep);
  conv_mfma<<<dim3(16, 9, 4), 256, 0, stream>>>(x, wprep, g0, g1);
  pool_kernel<<<2560, 256, 0, stream>>>(g1, g1p);
  corr_kernel<<<dim3(32, 32), 256, 0, stream>>>(g0, g1, g1p, out);
}

// Round 4
// 151.681 us; speedup vs baseline: 3.1458x; 1.0761x over previous
//
#include <hip/hip_runtime.h>
#include <hip/hip_bf16.h>

typedef __attribute__((ext_vector_type(8))) short short8;   // 8 bf16 (4 VGPRs)
typedef __attribute__((ext_vector_type(4))) short short4v;  // 4 bf16 (8 B)
typedef __attribute__((ext_vector_type(4))) float f32x4;    // MFMA acc

// Problem constants
static constexpr int CC = 320;   // input channels
static constexpr int HW = 1024;  // 32*32
static constexpr int C2 = 160;   // conv output channels
static constexpr size_t F_SZ = 32ull * HW * C2;  // floats per g tensor (5,242,880)
static constexpr int ROWF = 172;  // padded LDS row stride (floats), 16B-aligned rows
static constexpr int KSTEPS = 10; // K=320 in steps of 32
static constexpr int WPLANE = 160 * 40;  // shorts per (mat,hl) w-plane (padded 32->40)
static constexpr int WKS = 4 * WPLANE;   // shorts per k-step image (25600)

__device__ inline short bfh(float v) {
  __hip_bfloat16 h = __float2bfloat16(v);
  return *reinterpret_cast<short*>(&h);
}
__device__ inline float bff(short s) {
  union { unsigned u; float f; } c;
  c.u = ((unsigned)(unsigned short)s) << 16;
  return c.f;
}

// ---------------------------------------------------------------------------
// Kernel 0: pre-split w into bf16 (hi, lo) planes tiled exactly as the conv's
// LDS image: wp[ks][mat][hl][o 160][kk 40] (kk 32..39 = zero pad).
// ---------------------------------------------------------------------------
__global__ __launch_bounds__(256)
void wprep_kernel(const float* __restrict__ w0, const float* __restrict__ w1,
                  short* __restrict__ wp) {
  const int id = blockIdx.x * 256 + threadIdx.x;
  if (id >= KSTEPS * WKS) return;
  const int kk = id % 40;
  const int o = (id / 40) % 160;
  const int hl = (id / 6400) % 2;
  const int mat = (id / 12800) % 2;
  const int ks = id / 25600;
  short outv = 0;
  if (kk < 32) {
    const float v = (mat ? w1 : w0)[o * 320 + ks * 32 + kk];
    const short hb = bfh(v);
    outv = hl ? bfh(v - bff(hb)) : hb;
  }
  wp[id] = outv;
}

// ---------------------------------------------------------------------------
// Kernel 1: 1x1 convs via split-bf16 MFMA (wh*xh + wh*xl + wl*xh).
// (unchanged from round 3 — passing, ~30 µs)
// ---------------------------------------------------------------------------
__global__ __launch_bounds__(256)
void conv_mfma(const float* __restrict__ x, const short* __restrict__ wprep,
               float* __restrict__ g0, float* __restrict__ g1) {
  __shared__ __align__(16) short wL[4 * WPLANE];  // [mat*2+hl][160][40]
  __shared__ __align__(16) short xL[2][2560];     // [hl][px 64][kk 40]
  const int pxt = blockIdx.x;  // 0..15
  const int f = blockIdx.y;    // 0..8
  const int bb = blockIdx.z;   // 0..3
  const int tid = threadIdx.x;
  const int lane = tid & 63;
  const int wave = __builtin_amdgcn_readfirstlane(tid >> 6);
  const int lr = lane & 15, kg = lane >> 4;
  const int mat = wave >> 1;
  const int nf0 = (wave & 1) * 2;
  const bool active = mat ? (f >= 1) : (f < 8);
  const int tt = mat ? (f - 1) : f;
  const int p0 = pxt * 64;

  f32x4 acc[10][2];
#pragma unroll
  for (int m = 0; m < 10; ++m)
#pragma unroll
    for (int nfi = 0; nfi < 2; ++nfi)
#pragma unroll
      for (int r = 0; r < 4; ++r) acc[m][nfi][r] = 0.f;

  const size_t xbase = (size_t)bb * CC * 9216 + (size_t)f * 1024 + p0;
  float xr[2][4];
#pragma unroll
  for (int it = 0; it < 2; ++it) {
    const int item = tid + it * 256, px = item & 63, cg = item >> 6;
    const float* xp = x + xbase + (size_t)(cg * 4) * 9216 + px;
#pragma unroll
    for (int j = 0; j < 4; ++j) xr[it][j] = xp[(size_t)j * 9216];
  }

  for (int ks = 0; ks < KSTEPS; ++ks) {
    __syncthreads();  // LDS free (previous compute done)
    {
      const uint4* src = reinterpret_cast<const uint4*>(wprep + (size_t)ks * WKS);
      uint4* dst = reinterpret_cast<uint4*>(wL);
#pragma unroll
      for (int i = 0; i < 13; ++i) {
        const int idx = tid + i * 256;
        if (idx < 3200) dst[idx] = src[idx];
      }
    }
#pragma unroll
    for (int it = 0; it < 2; ++it) {
      const int item = tid + it * 256, px = item & 63, cg = item >> 6;
      short4v hv, lv;
#pragma unroll
      for (int j = 0; j < 4; ++j) {
        const float v = xr[it][j];
        const short hb = bfh(v);
        hv[j] = hb;
        lv[j] = bfh(v - bff(hb));
      }
      *reinterpret_cast<short4v*>(&xL[0][px * 40 + cg * 4]) = hv;
      *reinterpret_cast<short4v*>(&xL[1][px * 40 + cg * 4]) = lv;
    }
    __syncthreads();
    if (ks + 1 < KSTEPS) {
#pragma unroll
      for (int it = 0; it < 2; ++it) {
        const int item = tid + it * 256, px = item & 63, cg = item >> 6;
        const float* xp =
            x + xbase + (size_t)((ks + 1) * 32 + cg * 4) * 9216 + px;
#pragma unroll
        for (int j = 0; j < 4; ++j) xr[it][j] = xp[(size_t)j * 9216];
      }
    }
    if (active) {
      short8 bx[2][2];
#pragma unroll
      for (int nfi = 0; nfi < 2; ++nfi)
#pragma unroll
        for (int hl = 0; hl < 2; ++hl)
          bx[nfi][hl] = *reinterpret_cast<const short8*>(
              &xL[hl][((nf0 + nfi) * 16 + lr) * 40 + kg * 8]);
      const short* wbm = wL + mat * 2 * WPLANE;
#pragma unroll
      for (int m = 0; m < 10; ++m) {
        const short8 ah = *reinterpret_cast<const short8*>(
            &wbm[(m * 16 + lr) * 40 + kg * 8]);
        const short8 al = *reinterpret_cast<const short8*>(
            &wbm[WPLANE + (m * 16 + lr) * 40 + kg * 8]);
#pragma unroll
        for (int nfi = 0; nfi < 2; ++nfi) {
          acc[m][nfi] = __builtin_amdgcn_mfma_f32_16x16x32_bf16(
              ah, bx[nfi][0], acc[m][nfi], 0, 0, 0);
          acc[m][nfi] = __builtin_amdgcn_mfma_f32_16x16x32_bf16(
              ah, bx[nfi][1], acc[m][nfi], 0, 0, 0);
          acc[m][nfi] = __builtin_amdgcn_mfma_f32_16x16x32_bf16(
              al, bx[nfi][0], acc[m][nfi], 0, 0, 0);
        }
      }
    }
  }
  if (active) {
    float* __restrict__ g = mat ? g1 : g0;
    const size_t gb = (size_t)(bb * 8 + tt) * C2 * HW;
#pragma unroll
    for (int m = 0; m < 10; ++m) {
      const int o_b = m * 16 + kg * 4;
#pragma unroll
      for (int nfi = 0; nfi < 2; ++nfi) {
        const int px = p0 + (nf0 + nfi) * 16 + lr;
#pragma unroll
        for (int r = 0; r < 4; ++r)
          g[gb + (size_t)(o_b + r) * HW + px] = acc[m][nfi][r];
      }
    }
  }
}

// ---------------------------------------------------------------------------
// Kernel 2: 2x2 avg-pool over the px grid (unchanged from round 3)
// ---------------------------------------------------------------------------
__global__ __launch_bounds__(256)
void pool_kernel(const float* __restrict__ g1, float* __restrict__ g1p) {
  const int id = blockIdx.x * 256 + threadIdx.x;
  if (id >= 32 * 160 * 16 * 8) return;
  const int X4 = id & 7, Y = (id >> 3) & 15;
  const int row = id >> 7;  // 0..5119
  const float4* G4 = reinterpret_cast<const float4*>(g1) + (size_t)row * 256;
  const float4 a = G4[Y * 16 + X4];      // row 2Y
  const float4 c = G4[Y * 16 + X4 + 8];  // row 2Y+1
  float2 r;
  r.x = 0.25f * (a.x + a.y + c.x + c.y);
  r.y = 0.25f * (a.z + a.w + c.z + c.w);
  reinterpret_cast<float2*>(g1p)[(size_t)row * 128 + Y * 8 + X4] = r;
}

// ---------------------------------------------------------------------------
// Kernel 3: fused correlation + pyramid sampling.
// ROUND-4 CHANGE (the only change this round): 1-D grid with XCD-aware
// swizzle. flat = ((n&3)*32 + y)*8 + (n>>2), so XCD = flat%8 = n>>2: each
// XCD works one n-slice at a time (hot set g1-slice 640K + g1p 160K < 4M L2),
// y-neighbor blocks that share g1 rows are co-resident on the same L2.
// Bijective (1024 % 8 == 0). Compute phases identical to round 3.
// ---------------------------------------------------------------------------
__global__ __launch_bounds__(256)
void corr_kernel(const float* __restrict__ g0, const float* __restrict__ g1,
                 const float* __restrict__ g1p, float* __restrict__ out) {
  __shared__ float f0L[32 * ROWF];
  __shared__ float f1L[32 * ROWF];
  __shared__ float cornerL[8 * 32 * 9];  // [v][xx][u], stride 9
  const int flat = blockIdx.x;
  const int xcd = flat & 7;
  const int rr_ = flat >> 3;
  const int y = rr_ & 31;                   // 0..31
  const int n = (xcd << 2) | (rr_ >> 5);    // 0..31
  const int bb = n >> 3, q = n & 7;
  const int tid = threadIdx.x;
  const int xx = tid & 31;
  const int hi = tid >> 5;  // 0..7
  const float inv = 1.f / 160.f;
  const size_t obase = (size_t)(bb * 784 + q) * 1024 + (size_t)y * 32;
  const int chb = (bb * 8) * C2 + q * 20;  // + (c&7)*160 + (c>>3)

  // stage f0 row (transposed gather from g0)
  for (int idx = tid; idx < 5120; idx += 256) {
    const int c = idx >> 5, px = idx & 31;
    f0L[px * ROWF + c] =
        g0[(size_t)(chb + (c & 7) * C2 + (c >> 3)) * HW + y * 32 + px];
  }

  // ---- level 0 ----
  for (int dyi = 0; dyi < 7; ++dyi) {
    const int yy = y + dyi - 3;
    const bool inr = (unsigned)yy < 32u;
    __syncthreads();
    if (inr) {
      for (int idx = tid; idx < 5120; idx += 256) {
        const int c = idx >> 5, px = idx & 31;
        f1L[px * ROWF + c] =
            g1[(size_t)(chb + (c & 7) * C2 + (c >> 3)) * HW + yy * 32 + px];
      }
    }
    __syncthreads();
    if (hi < 7) {
      const int x2 = xx + hi - 3;
      float val = 0.f;
      if (inr && (unsigned)x2 < 32u) {
        const float4* a = reinterpret_cast<const float4*>(f0L + xx * ROWF);
        const float4* b = reinterpret_cast<const float4*>(f1L + x2 * ROWF);
        float4 s = {0.f, 0.f, 0.f, 0.f};
#pragma unroll 8
        for (int c4 = 0; c4 < 40; ++c4) {
          const float4 av = a[c4], bv = b[c4];
          s.x += av.x * bv.x;
          s.y += av.y * bv.y;
          s.z += av.z * bv.z;
          s.w += av.w * bv.w;
        }
        val = (s.x + s.y + s.z + s.w) * inv;
      }
      out[obase + (size_t)(hi * 7 + dyi) * 8192 + xx] = val;
    }
  }

  // ---- level 1: corner dots ----
  const int Y0 = (y >> 1) - 3;
  for (int v = 0; v < 8; ++v) {
    const int Y = Y0 + v;
    const bool inr = (unsigned)Y < 16u;
    __syncthreads();
    if (inr) {
      for (int idx = tid; idx < 2560; idx += 256) {
        const int c = idx >> 4, px = idx & 15;
        f1L[px * ROWF + c] =
            g1p[(size_t)(chb + (c & 7) * C2 + (c >> 3)) * 256 + Y * 16 + px];
      }
    }
    __syncthreads();
    const int X = (xx >> 1) - 3 + hi;
    float val = 0.f;
    if (inr && (unsigned)X < 16u) {
      const float4* a = reinterpret_cast<const float4*>(f0L + xx * ROWF);
      const float4* b = reinterpret_cast<const float4*>(f1L + X * ROWF);
      float4 s = {0.f, 0.f, 0.f, 0.f};
#pragma unroll 8
      for (int c4 = 0; c4 < 40; ++c4) {
        const float4 av = a[c4], bv = b[c4];
        s.x += av.x * bv.x;
        s.y += av.y * bv.y;
        s.z += av.z * bv.z;
        s.w += av.w * bv.w;
      }
      val = (s.x + s.y + s.z + s.w) * inv;
    }
    cornerL[(v * 32 + xx) * 9 + hi] = val;
  }
  __syncthreads();

  // ---- level 1: bilinear combine (weights 0 or 0.5) ----
  const float wy = (y & 1) ? 0.5f : 0.f;
  for (int idx = tid; idx < 32 * 49; idx += 256) {
    const int x2 = idx & 31;
    const int k = idx >> 5;  // 0..48
    const int dxi = k / 7, dyi = k % 7;
    const float wx = (x2 & 1) ? 0.5f : 0.f;
    const float* c0 = cornerL + (dyi * 32 + x2) * 9 + dxi;
    const float* c1 = c0 + 32 * 9;
    const float val = (1.f - wx) * ((1.f - wy) * c0[0] + wy * c1[0]) +
                      wx * ((1.f - wy) * c0[1] + wy * c1[1]);
    out[obase + (size_t)(49 + k) * 8192 + x2] = val;
  }
}

// ---------------------------------------------------------------------------
extern "C" void kernel_launch(void* const* d_in, const int* in_sizes, int n_in,
                              void* d_out, int out_size, void* d_ws,
                              size_t ws_size, hipStream_t stream) {
  const float* x = (const float*)d_in[0];
  const float* w0 = (const float*)d_in[1];
  const float* w1 = (const float*)d_in[2];
  float* g0 = (float*)d_ws;        // [4][8][160][1024]
  float* g1 = g0 + F_SZ;           // [4][8][160][1024]
  float* g1p = g1 + F_SZ;          // [4][8][160][256]
  short* wprep = (short*)(void*)g1p;  // overlapped: consumed before pool runs
  float* out = (float*)d_out;

  wprep_kernel<<<2000, 256, 0, stream>>>(w0, w1, wprep);
  conv_mfma<<<dim3(16, 9, 4), 256, 0, stream>>>(x, wprep, g0, g1);
  pool_kernel<<<2560, 256, 0, stream>>>(g1, g1p);
  corr_kernel<<<1024, 256, 0, stream>>>(g0, g1, g1p, out);
}

// Round 5
// 138.006 us; speedup vs baseline: 3.4575x; 1.0991x over previous
//
#include <hip/hip_runtime.h>
#include <hip/hip_bf16.h>

typedef __attribute__((ext_vector_type(8))) short short8;   // 8 bf16 (4 VGPRs)
typedef __attribute__((ext_vector_type(4))) short short4v;  // 4 bf16 (8 B)
typedef __attribute__((ext_vector_type(4))) float f32x4;    // MFMA acc

// Problem constants
static constexpr int CC = 320;   // input channels
static constexpr int HW = 1024;  // 32*32
static constexpr int C2 = 160;   // conv output channels
static constexpr size_t F_SZ = 32ull * HW * C2;  // floats per g tensor (5,242,880)
static constexpr int KSTEPS = 10; // K=320 in steps of 32
static constexpr int WPLANE = 160 * 40;  // shorts per (mat,hl) w-plane (padded 32->40)
static constexpr int WKS = 4 * WPLANE;   // shorts per k-step image (25600)
static constexpr int FS = 168;   // corr LDS row stride in shorts (336 B, 16B-aligned)

__device__ inline short bfh(float v) {
  __hip_bfloat16 h = __float2bfloat16(v);
  return *reinterpret_cast<short*>(&h);
}
__device__ inline float bff(short s) {
  union { unsigned u; float f; } c;
  c.u = ((unsigned)(unsigned short)s) << 16;
  return c.f;
}
__device__ inline unsigned packhl(float v0, float v1, unsigned& lo) {
  const short h0 = bfh(v0), h1 = bfh(v1);
  const short l0 = bfh(v0 - bff(h0)), l1 = bfh(v1 - bff(h1));
  lo = (unsigned)(unsigned short)l0 | ((unsigned)(unsigned short)l1 << 16);
  return (unsigned)(unsigned short)h0 | ((unsigned)(unsigned short)h1 << 16);
}

// ---------------------------------------------------------------------------
// Kernel 0: pre-split w into bf16 (hi, lo) planes (unchanged from round 3/4)
// ---------------------------------------------------------------------------
__global__ __launch_bounds__(256)
void wprep_kernel(const float* __restrict__ w0, const float* __restrict__ w1,
                  short* __restrict__ wp) {
  const int id = blockIdx.x * 256 + threadIdx.x;
  if (id >= KSTEPS * WKS) return;
  const int kk = id % 40;
  const int o = (id / 40) % 160;
  const int hl = (id / 6400) % 2;
  const int mat = (id / 12800) % 2;
  const int ks = id / 25600;
  short outv = 0;
  if (kk < 32) {
    const float v = (mat ? w1 : w0)[o * 320 + ks * 32 + kk];
    const short hb = bfh(v);
    outv = hl ? bfh(v - bff(hb)) : hb;
  }
  wp[id] = outv;
}

// ---------------------------------------------------------------------------
// Kernel 1: 1x1 convs via split-bf16 MFMA (unchanged from round 3/4)
// ---------------------------------------------------------------------------
__global__ __launch_bounds__(256)
void conv_mfma(const float* __restrict__ x, const short* __restrict__ wprep,
               float* __restrict__ g0, float* __restrict__ g1) {
  __shared__ __align__(16) short wL[4 * WPLANE];  // [mat*2+hl][160][40]
  __shared__ __align__(16) short xL[2][2560];     // [hl][px 64][kk 40]
  const int pxt = blockIdx.x;  // 0..15
  const int f = blockIdx.y;    // 0..8
  const int bb = blockIdx.z;   // 0..3
  const int tid = threadIdx.x;
  const int lane = tid & 63;
  const int wave = __builtin_amdgcn_readfirstlane(tid >> 6);
  const int lr = lane & 15, kg = lane >> 4;
  const int mat = wave >> 1;
  const int nf0 = (wave & 1) * 2;
  const bool active = mat ? (f >= 1) : (f < 8);
  const int tt = mat ? (f - 1) : f;
  const int p0 = pxt * 64;

  f32x4 acc[10][2];
#pragma unroll
  for (int m = 0; m < 10; ++m)
#pragma unroll
    for (int nfi = 0; nfi < 2; ++nfi)
#pragma unroll
      for (int r = 0; r < 4; ++r) acc[m][nfi][r] = 0.f;

  const size_t xbase = (size_t)bb * CC * 9216 + (size_t)f * 1024 + p0;
  float xr[2][4];
#pragma unroll
  for (int it = 0; it < 2; ++it) {
    const int item = tid + it * 256, px = item & 63, cg = item >> 6;
    const float* xp = x + xbase + (size_t)(cg * 4) * 9216 + px;
#pragma unroll
    for (int j = 0; j < 4; ++j) xr[it][j] = xp[(size_t)j * 9216];
  }

  for (int ks = 0; ks < KSTEPS; ++ks) {
    __syncthreads();  // LDS free (previous compute done)
    {
      const uint4* src = reinterpret_cast<const uint4*>(wprep + (size_t)ks * WKS);
      uint4* dst = reinterpret_cast<uint4*>(wL);
#pragma unroll
      for (int i = 0; i < 13; ++i) {
        const int idx = tid + i * 256;
        if (idx < 3200) dst[idx] = src[idx];
      }
    }
#pragma unroll
    for (int it = 0; it < 2; ++it) {
      const int item = tid + it * 256, px = item & 63, cg = item >> 6;
      short4v hv, lv;
#pragma unroll
      for (int j = 0; j < 4; ++j) {
        const float v = xr[it][j];
        const short hb = bfh(v);
        hv[j] = hb;
        lv[j] = bfh(v - bff(hb));
      }
      *reinterpret_cast<short4v*>(&xL[0][px * 40 + cg * 4]) = hv;
      *reinterpret_cast<short4v*>(&xL[1][px * 40 + cg * 4]) = lv;
    }
    __syncthreads();
    if (ks + 1 < KSTEPS) {
#pragma unroll
      for (int it = 0; it < 2; ++it) {
        const int item = tid + it * 256, px = item & 63, cg = item >> 6;
        const float* xp =
            x + xbase + (size_t)((ks + 1) * 32 + cg * 4) * 9216 + px;
#pragma unroll
        for (int j = 0; j < 4; ++j) xr[it][j] = xp[(size_t)j * 9216];
      }
    }
    if (active) {
      short8 bx[2][2];
#pragma unroll
      for (int nfi = 0; nfi < 2; ++nfi)
#pragma unroll
        for (int hl = 0; hl < 2; ++hl)
          bx[nfi][hl] = *reinterpret_cast<const short8*>(
              &xL[hl][((nf0 + nfi) * 16 + lr) * 40 + kg * 8]);
      const short* wbm = wL + mat * 2 * WPLANE;
#pragma unroll
      for (int m = 0; m < 10; ++m) {
        const short8 ah = *reinterpret_cast<const short8*>(
            &wbm[(m * 16 + lr) * 40 + kg * 8]);
        const short8 al = *reinterpret_cast<const short8*>(
            &wbm[WPLANE + (m * 16 + lr) * 40 + kg * 8]);
#pragma unroll
        for (int nfi = 0; nfi < 2; ++nfi) {
          acc[m][nfi] = __builtin_amdgcn_mfma_f32_16x16x32_bf16(
              ah, bx[nfi][0], acc[m][nfi], 0, 0, 0);
          acc[m][nfi] = __builtin_amdgcn_mfma_f32_16x16x32_bf16(
              ah, bx[nfi][1], acc[m][nfi], 0, 0, 0);
          acc[m][nfi] = __builtin_amdgcn_mfma_f32_16x16x32_bf16(
              al, bx[nfi][0], acc[m][nfi], 0, 0, 0);
        }
      }
    }
  }
  if (active) {
    float* __restrict__ g = mat ? g1 : g0;
    const size_t gb = (size_t)(bb * 8 + tt) * C2 * HW;
#pragma unroll
    for (int m = 0; m < 10; ++m) {
      const int o_b = m * 16 + kg * 4;
#pragma unroll
      for (int nfi = 0; nfi < 2; ++nfi) {
        const int px = p0 + (nf0 + nfi) * 16 + lr;
#pragma unroll
        for (int r = 0; r < 4; ++r)
          g[gb + (size_t)(o_b + r) * HW + px] = acc[m][nfi][r];
      }
    }
  }
}

// ---------------------------------------------------------------------------
// Kernel 2: 2x2 avg-pool (unchanged from round 3/4)
// ---------------------------------------------------------------------------
__global__ __launch_bounds__(256)
void pool_kernel(const float* __restrict__ g1, float* __restrict__ g1p) {
  const int id = blockIdx.x * 256 + threadIdx.x;
  if (id >= 32 * 160 * 16 * 8) return;
  const int X4 = id & 7, Y = (id >> 3) & 15;
  const int row = id >> 7;  // 0..5119
  const float4* G4 = reinterpret_cast<const float4*>(g1) + (size_t)row * 256;
  const float4 a = G4[Y * 16 + X4];      // row 2Y
  const float4 c = G4[Y * 16 + X4 + 8];  // row 2Y+1
  float2 r;
  r.x = 0.25f * (a.x + a.y + c.x + c.y);
  r.y = 0.25f * (a.z + a.w + c.z + c.w);
  reinterpret_cast<float2*>(g1p)[(size_t)row * 128 + Y * 8 + X4] = r;
}

// ---------------------------------------------------------------------------
// Kernel 3: correlation + pyramid sampling via split-bf16 MFMA.
// ROUND-5 CHANGE: dot products moved from VALU float4 loops to
// mfma_f32_16x16x32_bf16 (hh+hl+lh terms). Staging converts fp32 g-values to
// h/l bf16 planes (stride FS=168 shorts). MFMA tiles land in LDS scratch
// (S0 stride 33; S1 rolling 2-buffer stride 17); masked out-writes and the
// bilinear combine keep the round-4 output indexing exactly.
// XCD swizzle kept from round 4 (FETCH 100->23 MB win).
// Fragment conventions identical to conv_mfma (HW-validated): A[row][k],
// B[col][k] with row/col=lane&15, k=(lane>>4)*8+j -> D col=lane&15,
// row=(lane>>4)*4+reg.
// ---------------------------------------------------------------------------
__global__ __launch_bounds__(256)
void corr_kernel(const float* __restrict__ g0, const float* __restrict__ g1,
                 const float* __restrict__ g1p, float* __restrict__ out) {
  __shared__ __align__(16) short f0L[2][32 * FS];
  __shared__ __align__(16) short f1L[2][32 * FS];
  __shared__ float S0[32 * 33];
  __shared__ float S1[2][32 * 17];
  const int flat = blockIdx.x;
  const int xcd = flat & 7;
  const int rr_ = flat >> 3;
  const int y = rr_ & 31;                 // 0..31
  const int n = (xcd << 2) | (rr_ >> 5);  // 0..31
  const int bb = n >> 3, q = n & 7;
  const int tid = threadIdx.x;
  const int lane = tid & 63;
  const int wave = __builtin_amdgcn_readfirstlane(tid >> 6);
  const int lr = lane & 15, kg = lane >> 4;
  const int xx = tid & 31;
  const int hi = tid >> 5;  // 0..7
  const float inv = 1.f / 160.f;
  const size_t obase = (size_t)(bb * 784 + q) * 1024 + (size_t)y * 32;
  const int chb = (bb * 8) * C2 + q * 20;  // + (c&7)*160 + (c>>3)

  // ---- stage f0 row (32 px, split h/l, packed pair writes) ----
  for (int p = tid; p < 2560; p += 256) {
    const int cp = p >> 5, px = p & 31;  // cp 0..79
    const int c0 = 2 * cp;
    const float v0 =
        g0[(size_t)(chb + (c0 & 7) * C2 + (c0 >> 3)) * HW + y * 32 + px];
    const float v1 =
        g0[(size_t)(chb + ((c0 + 1) & 7) * C2 + ((c0 + 1) >> 3)) * HW + y * 32 + px];
    unsigned lo;
    const unsigned hp = packhl(v0, v1, lo);
    *reinterpret_cast<unsigned*>(&f0L[0][px * FS + c0]) = hp;
    *reinterpret_cast<unsigned*>(&f0L[1][px * FS + c0]) = lo;
  }
  __syncthreads();

  // ---- hoist A-fragments (f0 rows for this wave's m-tile) ----
  const int mi0 = wave >> 1, ni0 = wave & 1;
  short8 a0h[5], a0l[5];
#pragma unroll
  for (int ks = 0; ks < 5; ++ks) {
    a0h[ks] = *reinterpret_cast<const short8*>(
        &f0L[0][(mi0 * 16 + lr) * FS + ks * 32 + kg * 8]);
    a0l[ks] = *reinterpret_cast<const short8*>(
        &f0L[1][(mi0 * 16 + lr) * FS + ks * 32 + kg * 8]);
  }

  // ---- level 0: 7 dyi iterations, one 32x32 S-tile each ----
  for (int dyi = 0; dyi < 7; ++dyi) {
    const int yy = y + dyi - 3;
    const bool inr = (unsigned)yy < 32u;
    __syncthreads();  // f1L/S0 readers from prev iter done
    if (inr) {
      for (int p = tid; p < 2560; p += 256) {
        const int cp = p >> 5, px = p & 31;
        const int c0 = 2 * cp;
        const float v0 =
            g1[(size_t)(chb + (c0 & 7) * C2 + (c0 >> 3)) * HW + yy * 32 + px];
        const float v1 = g1[(size_t)(chb + ((c0 + 1) & 7) * C2 +
                                     ((c0 + 1) >> 3)) * HW + yy * 32 + px];
        unsigned lo;
        const unsigned hp = packhl(v0, v1, lo);
        *reinterpret_cast<unsigned*>(&f1L[0][px * FS + c0]) = hp;
        *reinterpret_cast<unsigned*>(&f1L[1][px * FS + c0]) = lo;
      }
    }
    __syncthreads();
    if (inr) {
      f32x4 acc = {0.f, 0.f, 0.f, 0.f};
#pragma unroll
      for (int ks = 0; ks < 5; ++ks) {
        const short8 bh = *reinterpret_cast<const short8*>(
            &f1L[0][(ni0 * 16 + lr) * FS + ks * 32 + kg * 8]);
        const short8 bl = *reinterpret_cast<const short8*>(
            &f1L[1][(ni0 * 16 + lr) * FS + ks * 32 + kg * 8]);
        acc = __builtin_amdgcn_mfma_f32_16x16x32_bf16(a0h[ks], bh, acc, 0, 0, 0);
        acc = __builtin_amdgcn_mfma_f32_16x16x32_bf16(a0h[ks], bl, acc, 0, 0, 0);
        acc = __builtin_amdgcn_mfma_f32_16x16x32_bf16(a0l[ks], bh, acc, 0, 0, 0);
      }
#pragma unroll
      for (int r = 0; r < 4; ++r)
        S0[(mi0 * 16 + kg * 4 + r) * 33 + ni0 * 16 + lr] = acc[r];
    }
    __syncthreads();
    if (hi < 7) {
      const int x2 = xx + hi - 3;
      const float val = (inr && (unsigned)x2 < 32u) ? S0[xx * 33 + x2] * inv : 0.f;
      out[obase + (size_t)(hi * 7 + dyi) * 8192 + xx] = val;
    }
  }

  // ---- level 1: 8 v iterations (pooled rows), rolling S1 + fused combine ----
  // reload A-fragments for L1 m-tiles (wave<2: mi = wave)
  short8 a1h[5], a1l[5];
  if (wave < 2) {
#pragma unroll
    for (int ks = 0; ks < 5; ++ks) {
      a1h[ks] = *reinterpret_cast<const short8*>(
          &f0L[0][(wave * 16 + lr) * FS + ks * 32 + kg * 8]);
      a1l[ks] = *reinterpret_cast<const short8*>(
          &f0L[1][(wave * 16 + lr) * FS + ks * 32 + kg * 8]);
    }
  }
  const int Y0 = (y >> 1) - 3;
  const float wy = (y & 1) ? 0.5f : 0.f;
  for (int v = 0; v < 8; ++v) {
    const int Y = Y0 + v;
    const bool inr = (unsigned)Y < 16u;
    __syncthreads();  // f1L readers + S1[v&1] readers (combine v-1) done
    if (inr) {
      for (int p = tid; p < 1280; p += 256) {
        const int cp = p >> 4, px = p & 15;  // cp 0..79
        const int c0 = 2 * cp;
        const float v0 =
            g1p[(size_t)(chb + (c0 & 7) * C2 + (c0 >> 3)) * 256 + Y * 16 + px];
        const float v1 = g1p[(size_t)(chb + ((c0 + 1) & 7) * C2 +
                                      ((c0 + 1) >> 3)) * 256 + Y * 16 + px];
        unsigned lo;
        const unsigned hp = packhl(v0, v1, lo);
        *reinterpret_cast<unsigned*>(&f1L[0][px * FS + c0]) = hp;
        *reinterpret_cast<unsigned*>(&f1L[1][px * FS + c0]) = lo;
      }
    }
    __syncthreads();
    if (wave < 2) {
      f32x4 acc = {0.f, 0.f, 0.f, 0.f};
      if (inr) {
#pragma unroll
        for (int ks = 0; ks < 5; ++ks) {
          const short8 bh = *reinterpret_cast<const short8*>(
              &f1L[0][lr * FS + ks * 32 + kg * 8]);
          const short8 bl = *reinterpret_cast<const short8*>(
              &f1L[1][lr * FS + ks * 32 + kg * 8]);
          acc = __builtin_amdgcn_mfma_f32_16x16x32_bf16(a1h[ks], bh, acc, 0, 0, 0);
          acc = __builtin_amdgcn_mfma_f32_16x16x32_bf16(a1h[ks], bl, acc, 0, 0, 0);
          acc = __builtin_amdgcn_mfma_f32_16x16x32_bf16(a1l[ks], bh, acc, 0, 0, 0);
        }
      }
#pragma unroll
      for (int r = 0; r < 4; ++r)
        S1[v & 1][(wave * 16 + kg * 4 + r) * 17 + lr] = acc[r];  // zeros if !inr
    }
    __syncthreads();
    if (v >= 1 && hi < 7) {
      const int dyi = v - 1;  // corners: row v-1 (c0) and row v (c1)
      const int Xl = (xx >> 1) - 3 + hi;
      const int Xr = Xl + 1;
      const float* t0 = S1[(v - 1) & 1];
      const float* t1 = S1[v & 1];
      const float a00 = ((unsigned)Xl < 16u) ? t0[xx * 17 + Xl] : 0.f;
      const float a01 = ((unsigned)Xr < 16u) ? t0[xx * 17 + Xr] : 0.f;
      const float a10 = ((unsigned)Xl < 16u) ? t1[xx * 17 + Xl] : 0.f;
      const float a11 = ((unsigned)Xr < 16u) ? t1[xx * 17 + Xr] : 0.f;
      const float wx = (xx & 1) ? 0.5f : 0.f;
      const float val = ((1.f - wx) * ((1.f - wy) * a00 + wy * a10) +
                         wx * ((1.f - wy) * a01 + wy * a11)) * inv;
      out[obase + (size_t)(49 + hi * 7 + dyi) * 8192 + xx] = val;
    }
  }
}

// ---------------------------------------------------------------------------
extern "C" void kernel_launch(void* const* d_in, const int* in_sizes, int n_in,
                              void* d_out, int out_size, void* d_ws,
                              size_t ws_size, hipStream_t stream) {
  const float* x = (const float*)d_in[0];
  const float* w0 = (const float*)d_in[1];
  const float* w1 = (const float*)d_in[2];
  float* g0 = (float*)d_ws;        // [4][8][160][1024]
  float* g1 = g0 + F_SZ;           // [4][8][160][1024]
  float* g1p = g1 + F_SZ;          // [4][8][160][256]
  short* wprep = (short*)(void*)g1p;  // overlapped: consumed before pool runs
  float* out = (float*)d_out;

  wprep_kernel<<<2000, 256, 0, stream>>>(w0, w1, wprep);
  conv_mfma<<<dim3(16, 9, 4), 256, 0, stream>>>(x, wprep, g0, g1);
  pool_kernel<<<2560, 256, 0, stream>>>(g1, g1p);
  corr_kernel<<<1024, 256, 0, stream>>>(g0, g1, g1p, out);
}

// Round 6
// 94.944 us; speedup vs baseline: 5.0257x; 1.4536x over previous
//
#include <hip/hip_runtime.h>
#include <hip/hip_bf16.h>

typedef __attribute__((ext_vector_type(8))) short short8;   // 8 bf16 (4 VGPRs)
typedef __attribute__((ext_vector_type(4))) float f32x4;    // MFMA acc

// Problem constants
static constexpr int HW = 1024;   // 32*32
static constexpr int C2 = 160;    // corr channel count
static constexpr int FS = 168;    // corr LDS row stride in shorts (336 B)
static constexpr int WPLANE = 160 * 40;  // shorts per (ks,mat,hl) w-plane
static constexpr int WKS = 4 * WPLANE;
static constexpr int KSTEPS = 10;
static constexpr size_t PL = 32ull * 1024 * 160;   // shorts per f-plane (10.49MB)
static constexpr size_t PPL = 32ull * 256 * 160;   // shorts per pooled plane

__device__ inline short bfh(float v) {
  __hip_bfloat16 h = __float2bfloat16(v);
  return *reinterpret_cast<short*>(&h);
}
__device__ inline float bff(short s) {
  union { unsigned u; float f; } c;
  c.u = ((unsigned)(unsigned short)s) << 16;
  return c.f;
}
__device__ inline unsigned packhl(float v0, float v1, unsigned& lo) {
  const short h0 = bfh(v0), h1 = bfh(v1);
  const short l0 = bfh(v0 - bff(h0)), l1 = bfh(v1 - bff(h1));
  lo = (unsigned)(unsigned short)l0 | ((unsigned)(unsigned short)l1 << 16);
  return (unsigned)(unsigned short)h0 | ((unsigned)(unsigned short)h1 << 16);
}

// ---------------------------------------------------------------------------
// Kernel 0: pre-split w into bf16 (hi,lo) planes, tiled per k-step (unchanged).
// wp[ks][mat][hl][o 160][kk 40], kk 32..39 zero.
// ---------------------------------------------------------------------------
__global__ __launch_bounds__(256)
void wprep_kernel(const float* __restrict__ w0, const float* __restrict__ w1,
                  short* __restrict__ wp) {
  const int id = blockIdx.x * 256 + threadIdx.x;
  if (id >= KSTEPS * WKS) return;
  const int kk = id % 40;
  const int o = (id / 40) % 160;
  const int hl = (id / 6400) % 2;
  const int mat = (id / 12800) % 2;
  const int ks = id / 25600;
  short outv = 0;
  if (kk < 32) {
    const float v = (mat ? w1 : w0)[o * 320 + ks * 32 + kk];
    const short hb = bfh(v);
    outv = hl ? bfh(v - bff(hb)) : hb;
  }
  wp[id] = outv;
}

// ---------------------------------------------------------------------------
// Kernel 1 (ROUND-6 REWRITE): fused 1x1 convs producing the interleaved
// split-bf16 f-tensors DIRECTLY.  Block = (px-tile 32, q-pair, batch), 4 waves.
// M = 80 rows (mat0 rows 0-39 = o qp*40..+39, mat1 rows 40-79), N = 9f x 32px,
// K = 320.  Wave (pxh = w&1, fpar = w>>1) computes all 5 m-tiles for its
// (px-half, frame-parity) subset; f-list = {fpar, fpar+2, ...}.
// Epilogue: two passes (mat0, mat1) transpose accs through LDS into complete
// rows f[n = bb*8+qp*2+ql][px][c = 8*(o%20)+tt] h/l, stored as coalesced uint4.
// ---------------------------------------------------------------------------
__global__ __launch_bounds__(256)
void conv_fused(const float* __restrict__ x, const short* __restrict__ wprep,
                short* __restrict__ f0bh, short* __restrict__ f0bl,
                short* __restrict__ f1bh, short* __restrict__ f1bl) {
  __shared__ __align__(16) short xB[2][288 * 40];  // [hl][col=f*32+px][kk]
  __shared__ __align__(16) short aL[2][80 * 40];   // [hl][gr][kk]
  const int pxt = blockIdx.x;  // 0..31
  const int qp = blockIdx.y;   // 0..3
  const int bb = blockIdx.z;   // 0..3
  const int tid = threadIdx.x;
  const int lane = tid & 63;
  const int wave = __builtin_amdgcn_readfirstlane(tid >> 6);
  const int lr = lane & 15, kg = lane >> 4;
  const int pxh = wave & 1;   // px half (16)
  const int fpar = wave >> 1; // frame parity: f in {fpar, fpar+2, ...}

  f32x4 acc[5][5];
#pragma unroll
  for (int mt = 0; mt < 5; ++mt)
#pragma unroll
    for (int fi = 0; fi < 5; ++fi)
#pragma unroll
      for (int r = 0; r < 4; ++r) acc[mt][fi][r] = 0.f;

  const size_t xbase = (size_t)bb * 320 * 9216 + (size_t)pxt * 32;

  for (int ks = 0; ks < KSTEPS; ++ks) {
    __syncthreads();
    // stage A (w rows for this q-pair): 800 uint4 plain copies
#pragma unroll
    for (int i = 0; i < 4; ++i) {
      const int idx = tid + i * 256;
      if (idx < 800) {
        const int u = idx % 5, gr = (idx / 5) % 80, hl = idx / 400;
        const int mat = gr >= 40;
        const int o = qp * 40 + (gr - mat * 40);
        const uint4* s = reinterpret_cast<const uint4*>(
            wprep + (size_t)((ks * 2 + mat) * 2 + hl) * WPLANE + o * 40) + u;
        reinterpret_cast<uint4*>(&aL[hl][gr * 40])[u] = *s;
      }
    }
    // stage x (convert fp32 -> h/l bf16): 4608 c-pairs
#pragma unroll
    for (int i = 0; i < 18; ++i) {
      const int id = tid + i * 256;
      const int px = id & 31, f = (id >> 5) % 9, kl2 = id / 288;  // kl2 0..15
      const float* xp =
          x + xbase + (size_t)(ks * 32 + 2 * kl2) * 9216 + f * 1024 + px;
      const float v0 = xp[0], v1 = xp[9216];
      unsigned lo;
      const unsigned hp = packhl(v0, v1, lo);
      *reinterpret_cast<unsigned*>(&xB[0][(f * 32 + px) * 40 + 2 * kl2]) = hp;
      *reinterpret_cast<unsigned*>(&xB[1][(f * 32 + px) * 40 + 2 * kl2]) = lo;
    }
    __syncthreads();
    // MFMA: hold A-frags, loop frames
    short8 Ah[5], Al[5];
#pragma unroll
    for (int mt = 0; mt < 5; ++mt) {
      Ah[mt] = *reinterpret_cast<const short8*>(&aL[0][(mt * 16 + lr) * 40 + kg * 8]);
      Al[mt] = *reinterpret_cast<const short8*>(&aL[1][(mt * 16 + lr) * 40 + kg * 8]);
    }
#pragma unroll
    for (int fi = 0; fi < 5; ++fi) {
      if (2 * fi + fpar < 9) {
        const int f = 2 * fi + fpar;
        const int col = (f * 32 + pxh * 16 + lr) * 40 + kg * 8;
        const short8 Bh = *reinterpret_cast<const short8*>(&xB[0][col]);
        const short8 Bl = *reinterpret_cast<const short8*>(&xB[1][col]);
#pragma unroll
        for (int mt = 0; mt < 5; ++mt) {
          acc[mt][fi] = __builtin_amdgcn_mfma_f32_16x16x32_bf16(Ah[mt], Bh, acc[mt][fi], 0, 0, 0);
          acc[mt][fi] = __builtin_amdgcn_mfma_f32_16x16x32_bf16(Ah[mt], Bl, acc[mt][fi], 0, 0, 0);
          acc[mt][fi] = __builtin_amdgcn_mfma_f32_16x16x32_bf16(Al[mt], Bh, acc[mt][fi], 0, 0, 0);
        }
      }
    }
  }

  // ---- epilogue: two mat-passes through LDS transpose (tL overlays xB) ----
  short* tL = &xB[0][0];  // [2 planes][64 rows][168]
#pragma unroll
  for (int m = 0; m < 2; ++m) {
    __syncthreads();  // previous readers of xB/tL done
#pragma unroll
    for (int mt = 0; mt < 5; ++mt)
#pragma unroll
      for (int fi = 0; fi < 5; ++fi) {
        const int f = 2 * fi + fpar;
        const int tt = f - m;
        if (f < 9 && (unsigned)tt < 8u) {
#pragma unroll
          for (int rr = 0; rr < 4; ++rr) {
            const int gr = mt * 16 + kg * 4 + rr;
            if ((gr >= 40) == (m == 1)) {  // row belongs to this mat
              const int rowl = gr - m * 40;
              const int ql = rowl / 20, r20 = rowl % 20;
              const int c = 8 * r20 + tt;
              const int row = ql * 32 + pxh * 16 + lr;
              const float v = acc[mt][fi][rr];
              const short h = bfh(v);
              const short l = bfh(v - bff(h));
              tL[row * FS + c] = h;
              tL[10752 + row * FS + c] = l;
            }
          }
        }
      }
    __syncthreads();
    // coalesced copy-out: 2560 uint4
#pragma unroll
    for (int i = 0; i < 10; ++i) {
      const int idx = tid + i * 256;
      const int plane = idx / 1280, rem = idx % 1280;
      const int row = rem / 20, c16 = rem % 20;
      const int ql = row >> 5, pxl = row & 31;
      const int n = bb * 8 + qp * 2 + ql;
      short* dst = (m == 0) ? (plane ? f0bl : f0bh) : (plane ? f1bl : f1bh);
      *reinterpret_cast<uint4*>(dst + ((size_t)n * 1024 + pxt * 32 + pxl) * 160 + c16 * 8) =
          *reinterpret_cast<const uint4*>(&tL[plane * 10752 + row * FS + c16 * 8]);
    }
  }
}

// ---------------------------------------------------------------------------
// Kernel 2: 2x2 avg-pool on the bf16 h/l planes (reconstruct, avg, re-split).
// ---------------------------------------------------------------------------
__global__ __launch_bounds__(256)
void pool_b(const short* __restrict__ f1bh, const short* __restrict__ f1bl,
            short* __restrict__ g1pbh, short* __restrict__ g1pbl) {
  const int id = blockIdx.x * 256 + threadIdx.x;  // 32*256*20
  if (id >= 32 * 256 * 20) return;
  const int c16 = id % 20;
  const int PX = (id / 20) & 255;
  const int n = id / (20 * 256);
  const int Y = PX >> 4, X = PX & 15;
  const int r0 = Y * 64 + X * 2;
  const size_t base = ((size_t)n * 1024 + r0) * 160 + c16 * 8;
  const short8 h00 = *reinterpret_cast<const short8*>(f1bh + base);
  const short8 h01 = *reinterpret_cast<const short8*>(f1bh + base + 160);
  const short8 h10 = *reinterpret_cast<const short8*>(f1bh + base + 32 * 160);
  const short8 h11 = *reinterpret_cast<const short8*>(f1bh + base + 33 * 160);
  const short8 l00 = *reinterpret_cast<const short8*>(f1bl + base);
  const short8 l01 = *reinterpret_cast<const short8*>(f1bl + base + 160);
  const short8 l10 = *reinterpret_cast<const short8*>(f1bl + base + 32 * 160);
  const short8 l11 = *reinterpret_cast<const short8*>(f1bl + base + 33 * 160);
  short8 ho, lo;
#pragma unroll
  for (int j = 0; j < 8; ++j) {
    const float v = 0.25f * ((bff(h00[j]) + bff(l00[j])) + (bff(h01[j]) + bff(l01[j])) +
                             (bff(h10[j]) + bff(l10[j])) + (bff(h11[j]) + bff(l11[j])));
    const short h = bfh(v);
    ho[j] = h;
    lo[j] = bfh(v - bff(h));
  }
  const size_t ob = ((size_t)n * 256 + PX) * 160 + c16 * 8;
  *reinterpret_cast<short8*>(g1pbh + ob) = ho;
  *reinterpret_cast<short8*>(g1pbl + ob) = lo;
}

// ---------------------------------------------------------------------------
// Kernel 3: correlation + pyramid sampling via split-bf16 MFMA.
// Same verified structure as round 5; staging is now plain uint4 copies from
// the pre-converted planes (no packhl, 4x fewer loads). XCD swizzle kept.
// MFMA chains split into 3 independent accumulators (hh/hl/lh).
// ---------------------------------------------------------------------------
__global__ __launch_bounds__(256)
void corr_kernel(const short* __restrict__ f0bh, const short* __restrict__ f0bl,
                 const short* __restrict__ f1bh, const short* __restrict__ f1bl,
                 const short* __restrict__ g1pbh, const short* __restrict__ g1pbl,
                 float* __restrict__ out) {
  __shared__ __align__(16) short f0L[2][32 * FS];
  __shared__ __align__(16) short f1L[2][32 * FS];
  __shared__ float S0[32 * 33];
  __shared__ float S1[2][32 * 17];
  const int flat = blockIdx.x;
  const int xcd = flat & 7;
  const int rr_ = flat >> 3;
  const int y = rr_ & 31;                 // 0..31
  const int n = (xcd << 2) | (rr_ >> 5);  // 0..31
  const int bb = n >> 3, q = n & 7;
  const int tid = threadIdx.x;
  const int lane = tid & 63;
  const int wave = __builtin_amdgcn_readfirstlane(tid >> 6);
  const int lr = lane & 15, kg = lane >> 4;
  const int xx = tid & 31;
  const int hi = tid >> 5;  // 0..7
  const float inv = 1.f / 160.f;
  const size_t obase = (size_t)(bb * 784 + q) * 1024 + (size_t)y * 32;

  // ---- stage f0 row: plain uint4 copies ----
#pragma unroll
  for (int i = 0; i < 5; ++i) {
    const int idx = tid + i * 256;  // < 1280
    const int plane = idx / 640, rem = idx % 640;
    const int px = rem / 20, c16 = rem % 20;
    const short* src = (plane ? f0bl : f0bh) + ((size_t)n * 1024 + y * 32 + px) * 160 + c16 * 8;
    *reinterpret_cast<uint4*>(&f0L[plane][px * FS + c16 * 8]) =
        *reinterpret_cast<const uint4*>(src);
  }
  __syncthreads();

  // ---- hoist A-fragments ----
  const int mi0 = wave >> 1, ni0 = wave & 1;
  short8 a0h[5], a0l[5];
#pragma unroll
  for (int ks = 0; ks < 5; ++ks) {
    a0h[ks] = *reinterpret_cast<const short8*>(&f0L[0][(mi0 * 16 + lr) * FS + ks * 32 + kg * 8]);
    a0l[ks] = *reinterpret_cast<const short8*>(&f0L[1][(mi0 * 16 + lr) * FS + ks * 32 + kg * 8]);
  }

  // ---- level 0 ----
  for (int dyi = 0; dyi < 7; ++dyi) {
    const int yy = y + dyi - 3;
    const bool inr = (unsigned)yy < 32u;
    __syncthreads();
    if (inr) {
#pragma unroll
      for (int i = 0; i < 5; ++i) {
        const int idx = tid + i * 256;
        const int plane = idx / 640, rem = idx % 640;
        const int px = rem / 20, c16 = rem % 20;
        const short* src = (plane ? f1bl : f1bh) + ((size_t)n * 1024 + yy * 32 + px) * 160 + c16 * 8;
        *reinterpret_cast<uint4*>(&f1L[plane][px * FS + c16 * 8]) =
            *reinterpret_cast<const uint4*>(src);
      }
    }
    __syncthreads();
    if (inr) {
      f32x4 aA = {0.f, 0.f, 0.f, 0.f}, aB = aA, aC = aA;
#pragma unroll
      for (int ks = 0; ks < 5; ++ks) {
        const short8 bh = *reinterpret_cast<const short8*>(&f1L[0][(ni0 * 16 + lr) * FS + ks * 32 + kg * 8]);
        const short8 bl = *reinterpret_cast<const short8*>(&f1L[1][(ni0 * 16 + lr) * FS + ks * 32 + kg * 8]);
        aA = __builtin_amdgcn_mfma_f32_16x16x32_bf16(a0h[ks], bh, aA, 0, 0, 0);
        aB = __builtin_amdgcn_mfma_f32_16x16x32_bf16(a0h[ks], bl, aB, 0, 0, 0);
        aC = __builtin_amdgcn_mfma_f32_16x16x32_bf16(a0l[ks], bh, aC, 0, 0, 0);
      }
#pragma unroll
      for (int r = 0; r < 4; ++r)
        S0[(mi0 * 16 + kg * 4 + r) * 33 + ni0 * 16 + lr] = (aA[r] + aB[r]) + aC[r];
    }
    __syncthreads();
    if (hi < 7) {
      const int x2 = xx + hi - 3;
      const float val = (inr && (unsigned)x2 < 32u) ? S0[xx * 33 + x2] * inv : 0.f;
      out[obase + (size_t)(hi * 7 + dyi) * 8192 + xx] = val;
    }
  }

  // ---- level 1: corner dots on pooled planes, rolling S1 + fused combine ----
  short8 a1h[5], a1l[5];
  if (wave < 2) {
#pragma unroll
    for (int ks = 0; ks < 5; ++ks) {
      a1h[ks] = *reinterpret_cast<const short8*>(&f0L[0][(wave * 16 + lr) * FS + ks * 32 + kg * 8]);
      a1l[ks] = *reinterpret_cast<const short8*>(&f0L[1][(wave * 16 + lr) * FS + ks * 32 + kg * 8]);
    }
  }
  const int Y0 = (y >> 1) - 3;
  const float wy = (y & 1) ? 0.5f : 0.f;
  for (int v = 0; v < 8; ++v) {
    const int Y = Y0 + v;
    const bool inr = (unsigned)Y < 16u;
    __syncthreads();
    if (inr) {
#pragma unroll
      for (int i = 0; i < 3; ++i) {
        const int idx = tid + i * 256;
        if (idx < 640) {
          const int plane = idx / 320, rem = idx % 320;
          const int px = rem / 20, c16 = rem % 20;
          const short* src = (plane ? g1pbl : g1pbh) + ((size_t)n * 256 + Y * 16 + px) * 160 + c16 * 8;
          *reinterpret_cast<uint4*>(&f1L[plane][px * FS + c16 * 8]) =
              *reinterpret_cast<const uint4*>(src);
        }
      }
    }
    __syncthreads();
    if (wave < 2) {
      f32x4 aA = {0.f, 0.f, 0.f, 0.f}, aB = aA, aC = aA;
      if (inr) {
#pragma unroll
        for (int ks = 0; ks < 5; ++ks) {
          const short8 bh = *reinterpret_cast<const short8*>(&f1L[0][lr * FS + ks * 32 + kg * 8]);
          const short8 bl = *reinterpret_cast<const short8*>(&f1L[1][lr * FS + ks * 32 + kg * 8]);
          aA = __builtin_amdgcn_mfma_f32_16x16x32_bf16(a1h[ks], bh, aA, 0, 0, 0);
          aB = __builtin_amdgcn_mfma_f32_16x16x32_bf16(a1h[ks], bl, aB, 0, 0, 0);
          aC = __builtin_amdgcn_mfma_f32_16x16x32_bf16(a1l[ks], bh, aC, 0, 0, 0);
        }
      }
#pragma unroll
      for (int r = 0; r < 4; ++r)
        S1[v & 1][(wave * 16 + kg * 4 + r) * 17 + lr] = (aA[r] + aB[r]) + aC[r];
    }
    __syncthreads();
    if (v >= 1 && hi < 7) {
      const int dyi = v - 1;
      const int Xl = (xx >> 1) - 3 + hi;
      const int Xr = Xl + 1;
      const float* t0 = S1[(v - 1) & 1];
      const float* t1 = S1[v & 1];
      const float a00 = ((unsigned)Xl < 16u) ? t0[xx * 17 + Xl] : 0.f;
      const float a01 = ((unsigned)Xr < 16u) ? t0[xx * 17 + Xr] : 0.f;
      const float a10 = ((unsigned)Xl < 16u) ? t1[xx * 17 + Xl] : 0.f;
      const float a11 = ((unsigned)Xr < 16u) ? t1[xx * 17 + Xr] : 0.f;
      const float wx = (xx & 1) ? 0.5f : 0.f;
      const float val = ((1.f - wx) * ((1.f - wy) * a00 + wy * a10) +
                         wx * ((1.f - wy) * a01 + wy * a11)) * inv;
      out[obase + (size_t)(49 + hi * 7 + dyi) * 8192 + xx] = val;
    }
  }
}

// ---------------------------------------------------------------------------
extern "C" void kernel_launch(void* const* d_in, const int* in_sizes, int n_in,
                              void* d_out, int out_size, void* d_ws,
                              size_t ws_size, hipStream_t stream) {
  const float* x = (const float*)d_in[0];
  const float* w0 = (const float*)d_in[1];
  const float* w1 = (const float*)d_in[2];
  short* f0bh = (short*)d_ws;
  short* f0bl = f0bh + PL;
  short* f1bh = f0bl + PL;
  short* f1bl = f1bh + PL;
  short* g1pbh = f1bl + PL;
  short* g1pbl = g1pbh + PPL;
  short* wprep = g1pbh;  // overlapped: consumed by conv before pool writes
  float* out = (float*)d_out;

  wprep_kernel<<<1000, 256, 0, stream>>>(w0, w1, wprep);
  conv_fused<<<dim3(32, 4, 4), 256, 0, stream>>>(x, wprep, f0bh, f0bl, f1bh, f1bl);
  pool_b<<<640, 256, 0, stream>>>(f1bh, f1bl, g1pbh, g1pbl);
  corr_kernel<<<1024, 256, 0, stream>>>(f0bh, f0bl, f1bh, f1bl, g1pbh, g1pbl, out);
}